// Round 10
// baseline (133.298 us; speedup 1.0000x reference)
//
#include <hip/hip_runtime.h>
#include <hip/hip_bf16.h>

// ---------------- problem dims ----------------
constexpr int Bn   = 256;
constexpr int NOA  = 64, NFA = 4;
constexpr int NOB  = 32, NFB = 3;
constexpr int NS   = 7;
constexpr int DIN  = 128, DL = 64, DG = 64, DH = 256;
constexpr int DGE  = 448;
constexpr int DINA = 704;
constexpr int DINB = 640;

typedef short  short8v __attribute__((ext_vector_type(8)));
typedef float  f32x4   __attribute__((ext_vector_type(4)));

__device__ __forceinline__ unsigned short f2bf(float x) {
  union { float f; unsigned int u; } a; a.f = x;
  unsigned int r = a.u + 0x7fff + ((a.u >> 16) & 1);   // RNE
  return (unsigned short)(r >> 16);
}

// B-frag layout (bf16, 8 elems per 16B chunk):
//   addr = (((s*KB + kb)*NCH + nchunk)*64 + lane)*8,  lane = lg*16 + lr,
//   element e of chunk = W[k = kb*32 + lg*8 + e][n = nchunk*16 + lr]
// One wave fragment load = 64 consecutive 16B chunks = 1KB fully coalesced.

// ================= pre1: xsum+rg + weight transposes =================
struct Pre1Args {
  const float *xA, *xB;
  const int *omA, *omB;
  const float *WgA, *bgA, *WgB, *bgB;
  float *rA, *rB;
  const float *WlA, *WlB, *W1A, *W1B, *W2A, *W2B;
  unsigned short *WlFA, *WlFB, *W1tA, *W1tB, *W1gtA, *W1gtB, *W2tA, *W2tB;
};

// xsum (masked over objects) + rg; wave f handles field f. 256 threads.
template<int O, int F>
__device__ void xsum_rg_body(const float* __restrict__ x, const int* __restrict__ om,
                             const float* __restrict__ Wg, const float* __restrict__ bg,
                             float* __restrict__ r, int b, float* smem) {
  float* xsm = smem;                                   // [F][128]
  const int t = threadIdx.x, f = t >> 6, lane = t & 63;
  if (f >= F) return;
  unsigned long long bal = __ballot(lane < O && om[(size_t)b * O + lane] != 0);
  float cnt = (float)__popcll(bal);
  float a0 = 0.f, a1 = 0.f;
  const float* xb = x + ((size_t)b * O * F + f) * DIN + lane;
#pragma unroll 8
  for (int o = 0; o < O; ++o) {
    float m = (float)((bal >> o) & 1ull);
    a0 += m * xb[(size_t)o * F * DIN];
    a1 += m * xb[(size_t)o * F * DIN + 64];
  }
  xsm[f * 128 + lane] = a0;
  xsm[f * 128 + lane + 64] = a1;
  asm volatile("s_waitcnt lgkmcnt(0)" ::: "memory");
  float acc = 0.f;
  const float* wp = Wg + lane;
#pragma unroll 8
  for (int i = 0; i < DIN; ++i) acc += xsm[f * 128 + i] * wp[(size_t)i * DG];
  acc += cnt * bg[lane];
  r[((size_t)b * F + f) * DG + lane] = fmaxf(acc, 0.f);
}

// row-major transpose (for W1g used by gpart): dst[s][n][k] = bf16(src[s][koff+k][n])
__device__ void wtrans_tile(const float* __restrict__ src, unsigned short* __restrict__ dst,
                            int N, int DINc, int koff, int Kout,
                            int s, int kt, int nt, float* smem) {
  float (*tile)[65] = reinterpret_cast<float(*)[65]>(smem);
  const int t = threadIdx.x;
#pragma unroll
  for (int i = 0; i < 16; ++i) {
    int rr = (t >> 6) + i * 4, c = t & 63;
    tile[rr][c] = src[((size_t)s * DINc + koff + kt * 64 + rr) * N + nt * 64 + c];
  }
  __syncthreads();
#pragma unroll
  for (int i = 0; i < 2; ++i) {
    int cidx = t + i * 256;
    int n = cidx >> 3, kc = (cidx & 7) * 8;
    union { short8v v; unsigned short e[8]; } u;
#pragma unroll
    for (int j = 0; j < 8; ++j) u.e[j] = f2bf(tile[kc + j][n]);
    *reinterpret_cast<short8v*>(dst + ((size_t)s * N + nt * 64 + n) * Kout + kt * 64 + kc) = u.v;
  }
}

// B-frag transpose for 256-col weights (NCH=16)
__device__ void wtrans_frag(const float* __restrict__ src, unsigned short* __restrict__ dst,
                            int DINc, int koff, int KB,
                            int s, int kt, int nt, float* smem) {
  float (*tile)[65] = reinterpret_cast<float(*)[65]>(smem);
  const int t = threadIdx.x;
#pragma unroll
  for (int i = 0; i < 16; ++i) {
    int rr = (t >> 6) + i * 4, c = t & 63;
    tile[rr][c] = src[((size_t)s * DINc + koff + kt * 64 + rr) * 256 + nt * 64 + c];
  }
  __syncthreads();
#pragma unroll
  for (int i = 0; i < 2; ++i) {
    int cidx = t + i * 256;
    int nl = cidx >> 3, kslot = cidx & 7;
    union { short8v v; unsigned short e[8]; } u;
#pragma unroll
    for (int j = 0; j < 8; ++j) u.e[j] = f2bf(tile[kslot * 8 + j][nl]);
    int kb = kt * 2 + (kslot >> 2);
    int lane = (kslot & 3) * 16 + (nl & 15);
    int nchunk = nt * 4 + (nl >> 4);
    *reinterpret_cast<short8v*>(
        dst + ((((size_t)s * KB + kb) * 16 + nchunk) * 64 + lane) * 8) = u.v;
  }
}

// Wl (128x64) -> B-frag with KB=4, NCH=4; block handles k-tile kt (64 rows)
__device__ void wl_frag(const float* __restrict__ src, unsigned short* __restrict__ dst,
                        int kt, float* smem) {
  float (*tile)[65] = reinterpret_cast<float(*)[65]>(smem);
  const int t = threadIdx.x;
#pragma unroll
  for (int i = 0; i < 16; ++i) {
    int rr = (t >> 6) + i * 4, c = t & 63;
    tile[rr][c] = src[(size_t)(kt * 64 + rr) * 64 + c];
  }
  __syncthreads();
#pragma unroll
  for (int i = 0; i < 2; ++i) {
    int cidx = t + i * 256;
    int nl = cidx >> 3, kslot = cidx & 7;
    union { short8v v; unsigned short e[8]; } u;
#pragma unroll
    for (int j = 0; j < 8; ++j) u.e[j] = f2bf(tile[kslot * 8 + j][nl]);
    int kb = kt * 2 + (kslot >> 2);
    int lane = (kslot & 3) * 16 + (nl & 15);
    int nchunk = nl >> 4;
    *reinterpret_cast<short8v*>(dst + (((size_t)kb * 4 + nchunk) * 64 + lane) * 8) = u.v;
  }
}

__global__ __launch_bounds__(256) void pre1_kernel(Pre1Args a) {
  __shared__ __align__(16) float smem[64 * 65];
  const int bid = blockIdx.x;
  if (bid < 256) {
    xsum_rg_body<NOA, NFA>(a.xA, a.omA, a.WgA, a.bgA, a.rA, bid, smem);
  } else if (bid < 512) {
    xsum_rg_body<NOB, NFB>(a.xB, a.omB, a.WgB, a.bgB, a.rB, bid - 256, smem);
  } else {
    int r = bid - 512;
    if (r < 2)        wl_frag(a.WlA, a.WlFA, r, smem);
    else if (r < 4)   wl_frag(a.WlB, a.WlFB, r - 2, smem);
    else if (r < 68)  { r -= 4;   wtrans_frag(a.W1A, a.W1tA, DINA, 0, 8,
                                    r / 16, (r % 16) >> 2, r & 3, smem); }
    else if (r < 104) { r -= 68;  wtrans_frag(a.W1B, a.W1tB, DINB, 0, 6,
                                    r / 12, (r % 12) >> 2, r & 3, smem); }
    else if (r < 216) { r -= 104; wtrans_tile(a.W1A, a.W1gtA, 256, DINA, NFA * DL, DGE,
                                    r / 28, (r % 28) >> 2, r & 3, smem); }
    else if (r < 300) { r -= 216; wtrans_tile(a.W1B, a.W1gtB, 256, DINB, NFB * DL, DGE,
                                    r / 28, (r % 28) >> 2, r & 3, smem); }
    else if (r < 364) { r -= 300; wtrans_frag(a.W2A, a.W2tA, DH, 0, 8,
                                    r / 16, (r % 16) >> 2, r & 3, smem); }
    else              { r -= 364; wtrans_frag(a.W2B, a.W2tB, DH, 0, 8,
                                    r / 16, (r % 16) >> 2, r & 3, smem); }
  }
}

// ================= pre2: gpart (MFMA) + reward =================
struct Pre2Args {
  const float *rA, *rB; const int *gm;
  const unsigned short *W1gtA, *W1gtB;
  const float *b1A, *b1B;
  float *g1A, *g1B;
  const float *rwW1, *rwb1, *rwW2, *rwb2, *rwW3, *rwb3;
  float *outR;
};

__device__ void gpart_body(const Pre2Args& a, int bx, int sg, unsigned char* smem) {
  auto Asb = reinterpret_cast<unsigned short(*)[72]>(smem);           // [64][72]
  auto Bsb = reinterpret_cast<unsigned short(*)[72]>(smem + 9216);    // [256][72]
  const int t = threadIdx.x, w = t >> 6, lane = t & 63;
  const int lr = lane & 15, lg = lane >> 4;
  const int m0 = bx * 64;
  const unsigned short* W1gt; const float* b1; float* g1; int S, sl;
  if (sg < NFA) { W1gt = a.W1gtA; b1 = a.b1A; g1 = a.g1A; S = NFA; sl = sg; }
  else          { W1gt = a.W1gtB; b1 = a.b1B; g1 = a.g1B; S = NFB; sl = sg - NFA; }

  f32x4 acc[4][4] = {};
  for (int kt = 0; kt < 7; ++kt) {
    __syncthreads();
    const int f = kt;
    const float* rsrc = (f < NFA) ? (a.rA + (size_t)f * DG) : (a.rB + (size_t)(f - NFA) * DG);
    const int rstride = (f < NFA) ? NFA * DG : NFB * DG;
#pragma unroll
    for (int i = 0; i < 2; ++i) {
      int c = t + i * 256;
      int row = c >> 3, kc = (c & 7) * 8;
      int b = m0 + row;
      float mk = (a.gm[((size_t)b * NS + sg) * NS + f] != 0) ? 1.f : 0.f;
      const float* rp = rsrc + (size_t)b * rstride + kc;
      union { short8v v; unsigned short e[8]; } u;
#pragma unroll
      for (int j = 0; j < 8; ++j) u.e[j] = f2bf(mk * rp[j]);
      *reinterpret_cast<short8v*>(&Asb[row][kc]) = u.v;
    }
#pragma unroll
    for (int i = 0; i < 8; ++i) {
      int c = t + i * 256;
      int n = c >> 3, kc = (c & 7) * 8;
      *reinterpret_cast<short8v*>(&Bsb[n][kc]) = *reinterpret_cast<const short8v*>(
          W1gt + ((size_t)sl * 256 + n) * DGE + kt * 64 + kc);
    }
    __syncthreads();
#pragma unroll
    for (int ks = 0; ks < 2; ++ks) {
      short8v af[4], bf[4];
#pragma unroll
      for (int mi = 0; mi < 4; ++mi)
        af[mi] = *reinterpret_cast<const short8v*>(&Asb[mi * 16 + lr][ks * 32 + lg * 8]);
#pragma unroll
      for (int ni = 0; ni < 4; ++ni)
        bf[ni] = *reinterpret_cast<const short8v*>(&Bsb[w * 64 + ni * 16 + lr][ks * 32 + lg * 8]);
#pragma unroll
      for (int mi = 0; mi < 4; ++mi)
#pragma unroll
        for (int ni = 0; ni < 4; ++ni)
          acc[mi][ni] = __builtin_amdgcn_mfma_f32_16x16x32_bf16(
              af[mi], bf[ni], acc[mi][ni], 0, 0, 0);
    }
  }
#pragma unroll
  for (int mi = 0; mi < 4; ++mi)
#pragma unroll
    for (int reg = 0; reg < 4; ++reg) {
      int b = m0 + mi * 16 + lg * 4 + reg;
#pragma unroll
      for (int ni = 0; ni < 4; ++ni) {
        int col = w * 64 + ni * 16 + lr;
        g1[((size_t)b * S + sl) * DH + col] = acc[mi][ni][reg] + b1[(size_t)sl * DH + col];
      }
    }
}

__device__ void reward_body(const Pre2Args& a, int b, unsigned char* smem) {
  float* Gs = reinterpret_cast<float*>(smem);
  float* h1 = Gs + DGE;
  float* red = h1 + DH;
  const int t = threadIdx.x;
  for (int j = t; j < DGE; j += 256)
    Gs[j] = (j < NFA * DG) ? a.rA[((size_t)b * NFA + (j >> 6)) * DG + (j & 63)]
                           : a.rB[((size_t)b * NFB + ((j - NFA * DG) >> 6)) * DG + (j & 63)];
  __syncthreads();
  float acc = a.rwb1[t];
  for (int j = 0; j < DGE; ++j) acc += Gs[j] * a.rwW1[(size_t)j * DH + t];
  h1[t] = (acc >= 0.f) ? acc : 0.01f * acc;
  __syncthreads();
  acc = a.rwb2[t];
  for (int j = 0; j < DH; ++j) acc += h1[j] * a.rwW2[(size_t)j * DH + t];
  acc = (acc >= 0.f) ? acc : 0.01f * acc;
  red[t] = acc * a.rwW3[t];
  __syncthreads();
  for (int off = 128; off > 0; off >>= 1) {
    if (t < off) red[t] += red[t + off];
    __syncthreads();
  }
  if (t == 0) a.outR[b] = red[0] + a.rwb3[0];
}

__global__ __launch_bounds__(256) void pre2_kernel(Pre2Args a) {
  __shared__ __align__(16) unsigned char smem[46080];
  const int bid = blockIdx.x;
  if (bid < 28) gpart_body(a, bid & 3, bid >> 2, smem);
  else          reward_body(a, bid - 28, smem);
}

// ================= fused: hl (from x) + decoder, all in one block =================
struct FusedArgs {
  const float *xA, *xB;
  const unsigned short *WlFA, *WlFB;
  const float *blA, *blB;
  const unsigned short *W1tA, *W1tB, *W2tA, *W2tB;
  const int *lmA, *lmB;
  const float *g1A, *g1B, *WpA, *WpB, *b2A, *b2B, *bpA, *bpB;
  float *outA, *outB;
};

template<int NO, int F>
__device__ __forceinline__ void fused_body(
    int blk,
    unsigned short* hl_lds /*[64][264]*/, unsigned short* scratch /*36864B*/,
    float* red /*[512]*/,
    const float* __restrict__ x, const unsigned short* __restrict__ WlF,
    const float* __restrict__ bl,
    const unsigned short* __restrict__ W1f, const unsigned short* __restrict__ W2f,
    const int* __restrict__ lm, const float* __restrict__ g1,
    const float* __restrict__ Wp, const float* __restrict__ b2,
    const float* __restrict__ bp, float* __restrict__ out) {
  constexpr int KB1 = 2 * F;
  const int t = threadIdx.x, w = t >> 6, lane = t & 63;
  const int lr = lane & 15, lg = lane >> 4;
  const int m0 = blk * 64;                 // 64 (b,o) rows per block

  // ---- Wl B-frags into registers (coalesced 1KB/wave loads) ----
  short8v bfwl[4][4];
#pragma unroll
  for (int kb = 0; kb < 4; ++kb)
#pragma unroll
    for (int ni = 0; ni < 4; ++ni)
      bfwl[kb][ni] = *reinterpret_cast<const short8v*>(
          WlF + (((size_t)kb * 4 + ni) * 64 + lane) * 8);

  f32x4 acc[4][4] = {};
  auto Asb = reinterpret_cast<unsigned short(*)[72]>(scratch);   // [256][72] x-staging

  // ---- phase 1: hl = relu(x @ Wl + bl) -> hl_lds[row][f*64+dl] ----
  {
    const float* xp_base = x + ((size_t)m0 * F + t) * DIN;       // mp-row t
    for (int k0 = 0; k0 < DIN; k0 += 64) {
      if (t < 64 * F) {
        const float* xp = xp_base + k0;
#pragma unroll
        for (int j = 0; j < 8; ++j) {
          float4 va = *(const float4*)(xp + j * 8);
          float4 vb = *(const float4*)(xp + j * 8 + 4);
          union { short8v v; unsigned short e[8]; } u;
          u.e[0] = f2bf(va.x); u.e[1] = f2bf(va.y); u.e[2] = f2bf(va.z); u.e[3] = f2bf(va.w);
          u.e[4] = f2bf(vb.x); u.e[5] = f2bf(vb.y); u.e[6] = f2bf(vb.z); u.e[7] = f2bf(vb.w);
          *reinterpret_cast<short8v*>(&Asb[t][j * 8]) = u.v;
        }
      }
      if (w < F) {
#pragma unroll
        for (int ks = 0; ks < 2; ++ks) {
          int kb = (k0 >> 5) + ks;
          short8v af[4];
#pragma unroll
          for (int mi = 0; mi < 4; ++mi)
            af[mi] = *reinterpret_cast<const short8v*>(
                &Asb[w * 64 + mi * 16 + lr][ks * 32 + lg * 8]);
#pragma unroll
          for (int mi = 0; mi < 4; ++mi)
#pragma unroll
            for (int ni = 0; ni < 4; ++ni)
              acc[mi][ni] = __builtin_amdgcn_mfma_f32_16x16x32_bf16(
                  af[mi], bfwl[kb][ni], acc[mi][ni], 0, 0, 0);
        }
      }
    }
    __syncthreads();
    if (w < F) {
#pragma unroll
      for (int mi = 0; mi < 4; ++mi)
#pragma unroll
        for (int reg = 0; reg < 4; ++reg) {
          int mp = w * 64 + mi * 16 + lg * 4 + reg;
          int row = mp / F, f = mp - row * F;
#pragma unroll
          for (int ni = 0; ni < 4; ++ni) {
            int dl = ni * 16 + lr;
            float v = fmaxf(acc[mi][ni][reg] + bl[dl], 0.f);
            hl_lds[row * 264 + f * 64 + dl] = f2bf(v);
            acc[mi][ni][reg] = 0.f;
          }
        }
    } else {
#pragma unroll
      for (int mi = 0; mi < 4; ++mi)
#pragma unroll
        for (int ni = 0; ni < 4; ++ni)
#pragma unroll
          for (int reg = 0; reg < 4; ++reg) acc[mi][ni][reg] = 0.f;
    }
    __syncthreads();
  }

  // ---- phase 2: per-s decode ----
  unsigned short* h1s = scratch;          // [64][264] aliases Asb (dead now)
  const short8v zero8 = {0, 0, 0, 0, 0, 0, 0, 0};

  for (int s = 0; s < F; ++s) {
    // masks (rows 0..31 -> mkl, 32..63 -> mkh)
    unsigned mkl = 0, mkh = 0;
#pragma unroll
    for (int f = 0; f < F; ++f) {
      if (NO == 64) {
        unsigned bit = (lm[((size_t)blk * F + s) * F + f] != 0) ? 1u : 0u;
        mkl |= bit << f; mkh |= bit << f;
      } else {
        int b0 = blk * 2;
        if (lm[((size_t)b0 * F + s) * F + f])       mkl |= 1u << f;
        if (lm[((size_t)(b0 + 1) * F + s) * F + f]) mkh |= 1u << f;
      }
    }
    float g1v[2][4];
#pragma unroll
    for (int ni = 0; ni < 4; ++ni) {
      int col = w * 64 + ni * 16 + lr;
      if (NO == 64) {
        g1v[0][ni] = g1[((size_t)blk * F + s) * DH + col];
        g1v[1][ni] = g1v[0][ni];
      } else {
        g1v[0][ni] = g1[((size_t)(blk * 2) * F + s) * DH + col];
        g1v[1][ni] = g1[((size_t)(blk * 2 + 1) * F + s) * DH + col];
      }
    }

    // GEMM1: A from hl_lds, B streamed coalesced from W1f
#pragma unroll
    for (int kb = 0; kb < KB1; ++kb) {
      const int f = kb >> 1;
      short8v af[4], bf[4];
#pragma unroll
      for (int mi = 0; mi < 4; ++mi)
        af[mi] = *reinterpret_cast<const short8v*>(
            hl_lds + (mi * 16 + lr) * 264 + kb * 32 + lg * 8);
      const bool blo = (mkl >> f) & 1, bhi = (mkh >> f) & 1;
#pragma unroll
      for (int mi = 0; mi < 4; ++mi) {
        const bool ok = (mi < 2) ? blo : bhi;
        af[mi] = ok ? af[mi] : zero8;
      }
      const unsigned short* bb =
          W1f + (((size_t)s * KB1 + kb) * 16 + w * 4) * 512 + lane * 8;
#pragma unroll
      for (int ni = 0; ni < 4; ++ni)
        bf[ni] = *reinterpret_cast<const short8v*>(bb + ni * 512);
#pragma unroll
      for (int mi = 0; mi < 4; ++mi)
#pragma unroll
        for (int ni = 0; ni < 4; ++ni)
          acc[mi][ni] = __builtin_amdgcn_mfma_f32_16x16x32_bf16(
              af[mi], bf[ni], acc[mi][ni], 0, 0, 0);
    }

    // epi1: +g1, lrelu -> h1s
#pragma unroll
    for (int mi = 0; mi < 4; ++mi) {
      int gi = (NO == 32) ? (mi >> 1) : 0;
#pragma unroll
      for (int reg = 0; reg < 4; ++reg) {
        int row = mi * 16 + lg * 4 + reg;
#pragma unroll
        for (int ni = 0; ni < 4; ++ni) {
          int col = w * 64 + ni * 16 + lr;
          float v = acc[mi][ni][reg] + g1v[gi][ni];
          v = (v >= 0.f) ? v : 0.01f * v;
          h1s[row * 264 + col] = f2bf(v);
          acc[mi][ni][reg] = 0.f;
        }
      }
    }
    __syncthreads();

    // GEMM2: A from h1s, B streamed from W2f
#pragma unroll
    for (int kb = 0; kb < 8; ++kb) {
      short8v af[4], bf[4];
#pragma unroll
      for (int mi = 0; mi < 4; ++mi)
        af[mi] = *reinterpret_cast<const short8v*>(
            h1s + (mi * 16 + lr) * 264 + kb * 32 + lg * 8);
      const unsigned short* bb =
          W2f + (((size_t)s * 8 + kb) * 16 + w * 4) * 512 + lane * 8;
#pragma unroll
      for (int ni = 0; ni < 4; ++ni)
        bf[ni] = *reinterpret_cast<const short8v*>(bb + ni * 512);
#pragma unroll
      for (int mi = 0; mi < 4; ++mi)
#pragma unroll
        for (int ni = 0; ni < 4; ++ni)
          acc[mi][ni] = __builtin_amdgcn_mfma_f32_16x16x32_bf16(
              af[mi], bf[ni], acc[mi][ni], 0, 0, 0);
    }

    // epi2: lrelu(+b2), Wp, shfl reduce, store
    float part[4][4][2] = {};
    const float* Wps = Wp + (size_t)s * DH * 2;
    const float* b2s = b2 + (size_t)s * DH;
#pragma unroll
    for (int ni = 0; ni < 4; ++ni) {
      int col = w * 64 + ni * 16 + lr;
      float wp0 = Wps[col * 2 + 0], wp1 = Wps[col * 2 + 1], bb2 = b2s[col];
#pragma unroll
      for (int mi = 0; mi < 4; ++mi)
#pragma unroll
        for (int reg = 0; reg < 4; ++reg) {
          float v = acc[mi][ni][reg] + bb2;
          v = (v >= 0.f) ? v : 0.01f * v;
          part[mi][reg][0] += v * wp0;
          part[mi][reg][1] += v * wp1;
          acc[mi][ni][reg] = 0.f;
        }
    }
#pragma unroll
    for (int off = 1; off < 16; off <<= 1)
#pragma unroll
      for (int mi = 0; mi < 4; ++mi)
#pragma unroll
        for (int reg = 0; reg < 4; ++reg) {
          part[mi][reg][0] += __shfl_xor(part[mi][reg][0], off, 64);
          part[mi][reg][1] += __shfl_xor(part[mi][reg][1], off, 64);
        }
    if (lr == 0)
#pragma unroll
      for (int mi = 0; mi < 4; ++mi)
#pragma unroll
        for (int reg = 0; reg < 4; ++reg) {
          int row = mi * 16 + lg * 4 + reg;
          red[((size_t)w * 64 + row) * 2 + 0] = part[mi][reg][0];
          red[((size_t)w * 64 + row) * 2 + 1] = part[mi][reg][1];
        }
    __syncthreads();
    if (t < 128) {
      int row = t >> 1, p = t & 1;
      float sum = red[(0 * 64 + row) * 2 + p] + red[(1 * 64 + row) * 2 + p]
                + red[(2 * 64 + row) * 2 + p] + red[(3 * 64 + row) * 2 + p];
      out[((size_t)(m0 + row) * F + s) * 2 + p] = sum + bp[(size_t)s * 2 + p];
    }
    __syncthreads();                       // protect red & h1s for next s
  }
}

__global__ __launch_bounds__(256) void fused_kernel(FusedArgs a) {
  __shared__ __align__(16) unsigned short hl_lds[64 * 264];   // 33,792 B
  __shared__ __align__(16) unsigned short scratch[256 * 72];  // 36,864 B
  __shared__ __align__(16) float red[512];                    //  2,048 B
  const int bid = blockIdx.x;
  if (bid < 256) {
    fused_body<NOA, NFA>(bid, hl_lds, scratch, red,
                         a.xA, a.WlFA, a.blA, a.W1tA, a.W2tA,
                         a.lmA, a.g1A, a.WpA, a.b2A, a.bpA, a.outA);
  } else {
    fused_body<NOB, NFB>(bid - 256, hl_lds, scratch, red,
                         a.xB, a.WlFB, a.blB, a.W1tB, a.W2tB,
                         a.lmB, a.g1B, a.WpB, a.b2B, a.bpB, a.outB);
  }
}

// ================= launcher =================
extern "C" void kernel_launch(void* const* d_in, const int* in_sizes, int n_in,
                              void* d_out, int out_size, void* d_ws, size_t ws_size,
                              hipStream_t stream) {
  const float* x_A  = (const float*)d_in[0];
  const float* x_B  = (const float*)d_in[1];
  const int*   gm   = (const int*)d_in[2];
  const int*   lmA  = (const int*)d_in[3];
  const int*   lmB  = (const int*)d_in[4];
  const int*   omA  = (const int*)d_in[5];
  const int*   omB  = (const int*)d_in[6];
  const float* Wl_A = (const float*)d_in[7];
  const float* bl_A = (const float*)d_in[8];
  const float* Wg_A = (const float*)d_in[9];
  const float* bg_A = (const float*)d_in[10];
  const float* Wl_B = (const float*)d_in[11];
  const float* bl_B = (const float*)d_in[12];
  const float* Wg_B = (const float*)d_in[13];
  const float* bg_B = (const float*)d_in[14];
  const float* W1_A = (const float*)d_in[15];
  const float* b1_A = (const float*)d_in[16];
  const float* W2_A = (const float*)d_in[17];
  const float* b2_A = (const float*)d_in[18];
  const float* Wp_A = (const float*)d_in[19];
  const float* bp_A = (const float*)d_in[20];
  const float* W1_B = (const float*)d_in[21];
  const float* b1_B = (const float*)d_in[22];
  const float* W2_B = (const float*)d_in[23];
  const float* b2_B = (const float*)d_in[24];
  const float* Wp_B = (const float*)d_in[25];
  const float* bp_B = (const float*)d_in[26];
  const float* rwW1 = (const float*)d_in[27];
  const float* rwb1 = (const float*)d_in[28];
  const float* rwW2 = (const float*)d_in[29];
  const float* rwb2 = (const float*)d_in[30];
  const float* rwW3 = (const float*)d_in[31];
  const float* rwb3 = (const float*)d_in[32];

  // ---- f32 workspace ----
  float* ws   = (float*)d_ws;
  float* rA   = ws;                        //  65,536
  float* rB   = rA + 65536;                //  49,152
  float* g1A  = rB + 49152;                // 262,144
  float* g1B  = g1A + 262144;              // 196,608
  // ---- bf16 (ushort) frag buffers ----
  unsigned short* us    = (unsigned short*)(g1B + 196608);
  unsigned short* W1tA  = us;              // 262,144
  unsigned short* W1tB  = W1tA + 262144;   // 147,456
  unsigned short* W2tA  = W1tB + 147456;   // 262,144
  unsigned short* W2tB  = W2tA + 262144;   // 196,608
  unsigned short* W1gtA = W2tB + 196608;   // 458,752 (row-major)
  unsigned short* W1gtB = W1gtA + 458752;  // 344,064 (row-major)
  unsigned short* WlFA  = W1gtB + 344064;  //   8,192
  unsigned short* WlFB  = WlFA + 8192;     //   8,192

  float* outA = (float*)d_out;             // (256,64,4,2)
  float* outB = outA + 131072;             // (256,32,3,2)
  float* outR = outA + 180224;             // (256,)

  Pre1Args p1;
  p1.xA = x_A; p1.xB = x_B; p1.omA = omA; p1.omB = omB;
  p1.WgA = Wg_A; p1.bgA = bg_A; p1.WgB = Wg_B; p1.bgB = bg_B;
  p1.rA = rA; p1.rB = rB;
  p1.WlA = Wl_A; p1.WlB = Wl_B; p1.W1A = W1_A; p1.W1B = W1_B;
  p1.W2A = W2_A; p1.W2B = W2_B;
  p1.WlFA = WlFA; p1.WlFB = WlFB; p1.W1tA = W1tA; p1.W1tB = W1tB;
  p1.W1gtA = W1gtA; p1.W1gtB = W1gtB; p1.W2tA = W2tA; p1.W2tB = W2tB;

  Pre2Args p2;
  p2.rA = rA; p2.rB = rB; p2.gm = gm; p2.W1gtA = W1gtA; p2.W1gtB = W1gtB;
  p2.b1A = b1_A; p2.b1B = b1_B; p2.g1A = g1A; p2.g1B = g1B;
  p2.rwW1 = rwW1; p2.rwb1 = rwb1; p2.rwW2 = rwW2; p2.rwb2 = rwb2;
  p2.rwW3 = rwW3; p2.rwb3 = rwb3; p2.outR = outR;

  FusedArgs fa;
  fa.xA = x_A; fa.xB = x_B; fa.WlFA = WlFA; fa.WlFB = WlFB;
  fa.blA = bl_A; fa.blB = bl_B;
  fa.W1tA = W1tA; fa.W1tB = W1tB; fa.W2tA = W2tA; fa.W2tB = W2tB;
  fa.lmA = lmA; fa.lmB = lmB; fa.g1A = g1A; fa.g1B = g1B;
  fa.WpA = Wp_A; fa.WpB = Wp_B; fa.b2A = b2_A; fa.b2B = b2_B;
  fa.bpA = bp_A; fa.bpB = bp_B; fa.outA = outA; fa.outB = outB;

  pre1_kernel<<<924, 256, 0, stream>>>(p1);
  pre2_kernel<<<284, 256, 0, stream>>>(p2);
  fused_kernel<<<384, 256, 0, stream>>>(fa);
}